// Round 9
// baseline (594.296 us; speedup 1.0000x reference)
//
#include <hip/hip_runtime.h>
#include <hip/hip_bf16.h>

// DIAGNOSTIC ROUND: all three kernels repeat their idempotent work REP times
// so each dispatch exceeds the ~41us harness fill kernels and lands in rocprof
// top-5 with counters. Real per-kernel dur = dur/REP. Production: REP=1.
#define REP 8

#define TOK_T 8
#define TOK_H 32
#define TOK_W 32
#define NTOK 8192
#define BATCH 2
#define DMODEL 256
#define D3 768
#define NHEADS 8
#define DHEAD 32

using short8  = __attribute__((ext_vector_type(8))) short;
using ushort8 = __attribute__((ext_vector_type(8))) unsigned short;
using f32x4   = __attribute__((ext_vector_type(4))) float;
using f32x2   = __attribute__((ext_vector_type(2))) float;

// RNE f32->bf16 via HIP intrinsic (compiler emits v_cvt_pk_bf16_f32 pairs;
// m240: scalar-cast path beats hand-written asm)
__device__ __forceinline__ ushort f2bf(float f) {
  __hip_bfloat16 h = __float2bfloat16(f);
  return *reinterpret_cast<ushort*>(&h);
}
__device__ __forceinline__ float bf2f(ushort u) {
  union { unsigned u; float f; } v; v.u = ((unsigned)u) << 16;
  return v.f;
}
// unpack one u32 (2 bf16) -> float2
__device__ __forceinline__ f32x2 bfpair(unsigned u) {
  union { unsigned u; float f; } lo, hi;
  lo.u = u << 16;
  hi.u = u & 0xffff0000u;
  f32x2 r; r[0] = lo.f; r[1] = hi.f;
  return r;
}

// ---------------- fused-convert GEMM: C = A[M,256] * B[N,256]^T ----------------
template<int TBM, int TBN, int NW, bool AF32, bool OUTBF16>
__global__ __launch_bounds__(NW * 64, 4) void gemm_fused(const void* __restrict__ Av,
                                                         const float* __restrict__ B,
                                                         void* __restrict__ Cv,
                                                         int ldc) {
  constexpr int NCW = TBN / 64;
  constexpr int NWR = NW / NCW;
  constexpr int MR  = TBM / (NWR * 16);
  constexpr int CHA = TBM * 4;
  constexpr int CHB = TBN * 4;
  constexpr int NT  = NW * 64;
  constexpr int CPT = (CHA + CHB) / NT;
  constexpr int SA  = CHA / NT;
  constexpr int ATILE = TBM * 32;
  constexpr int BTILE = TBN * 32;

  __shared__ __align__(16) ushort sm[2][ATILE + BTILE];

  const int tid  = threadIdx.x;
  const int lane = tid & 63;
  const int wid  = tid >> 6;
  const int wr   = wid / NCW;
  const int wc   = wid % NCW;
  const int bm   = blockIdx.y * TBM;   // slow axis
  const int bn   = blockIdx.x * TBN;   // fast axis
  const int fr   = lane & 15;
  const int kb   = lane >> 4;

  float4  laf[SA > 0 ? SA : 1][2];
  ushort8 lab[SA > 0 ? SA : 1];
  float4  lbf[CPT - SA][2];

  auto load = [&](int kt) {
#pragma unroll
    for (int s = 0; s < SA; ++s) {
      int cc = tid + s * NT;
      int r = cc >> 2, sl = cc & 3;
      if constexpr (AF32) {
        const float* p = (const float*)Av + (size_t)(bm + r) * 256 + kt + sl * 8;
        laf[s][0] = *(const float4*)p;
        laf[s][1] = *(const float4*)(p + 4);
      } else {
        lab[s] = *(const ushort8*)((const ushort*)Av + (size_t)(bm + r) * 256 + kt + sl * 8);
      }
    }
#pragma unroll
    for (int s = 0; s < CPT - SA; ++s) {
      int cc = tid + (s + SA) * NT - CHA;
      int r = cc >> 2, sl = cc & 3;
      const float* p = B + (size_t)(bn + r) * 256 + kt + sl * 8;
      lbf[s][0] = *(const float4*)p;
      lbf[s][1] = *(const float4*)(p + 4);
    }
  };
  auto stow = [&](int buf) {
#pragma unroll
    for (int s = 0; s < SA; ++s) {
      int cc = tid + s * NT;
      int r = cc >> 2, sl = cc & 3;
      int sck = r * 4 + (sl ^ ((r >> 1) & 3));
      ushort8 v;
      if constexpr (AF32) {
        v[0] = f2bf(laf[s][0].x); v[1] = f2bf(laf[s][0].y);
        v[2] = f2bf(laf[s][0].z); v[3] = f2bf(laf[s][0].w);
        v[4] = f2bf(laf[s][1].x); v[5] = f2bf(laf[s][1].y);
        v[6] = f2bf(laf[s][1].z); v[7] = f2bf(laf[s][1].w);
      } else v = lab[s];
      *(ushort8*)&sm[buf][sck * 8] = v;
    }
#pragma unroll
    for (int s = 0; s < CPT - SA; ++s) {
      int cc = tid + (s + SA) * NT - CHA;
      int r = cc >> 2, sl = cc & 3;
      int sck = r * 4 + (sl ^ ((r >> 1) & 3));
      ushort8 v;
      v[0] = f2bf(lbf[s][0].x); v[1] = f2bf(lbf[s][0].y);
      v[2] = f2bf(lbf[s][0].z); v[3] = f2bf(lbf[s][0].w);
      v[4] = f2bf(lbf[s][1].x); v[5] = f2bf(lbf[s][1].y);
      v[6] = f2bf(lbf[s][1].z); v[7] = f2bf(lbf[s][1].w);
      *(ushort8*)&sm[buf][ATILE + sck * 8] = v;
    }
  };

  for (int rep = 0; rep < REP; ++rep) {
    f32x4 acc[MR][4] = {};

    load(0);
    stow(0);
    __syncthreads();

    for (int it = 0; it < 8; ++it) {
      const int cur = it & 1;
      if (it < 7) load((it + 1) * 32);

      short8 af[MR], bf8[4];
#pragma unroll
      for (int m = 0; m < MR; ++m) {
        int r  = wr * (MR * 16) + m * 16 + fr;
        int ck = r * 4 + (kb ^ ((r >> 1) & 3));
        af[m] = *(const short8*)&sm[cur][ck * 8];
      }
#pragma unroll
      for (int n = 0; n < 4; ++n) {
        int r  = wc * 64 + n * 16 + fr;
        int ck = r * 4 + (kb ^ ((r >> 1) & 3));
        bf8[n] = *(const short8*)&sm[cur][ATILE + ck * 8];
      }
#pragma unroll
      for (int m = 0; m < MR; ++m)
#pragma unroll
        for (int n = 0; n < 4; ++n)
          acc[m][n] = __builtin_amdgcn_mfma_f32_16x16x32_bf16(af[m], bf8[n], acc[m][n], 0, 0, 0);

      if (it < 7) {
        stow(cur ^ 1);
        __syncthreads();
      }
    }

    if constexpr (OUTBF16) {
      ushort* C = (ushort*)Cv;
#pragma unroll
      for (int m = 0; m < MR; ++m)
#pragma unroll
        for (int n = 0; n < 4; ++n)
#pragma unroll
          for (int j = 0; j < 4; ++j) {
            int row = bm + wr * (MR * 16) + m * 16 + kb * 4 + j;
            int col = bn + wc * 64 + n * 16 + fr;
            C[(size_t)row * ldc + col] = f2bf(acc[m][n][j]);
          }
    } else {
      float* C = (float*)Cv;
#pragma unroll
      for (int m = 0; m < MR; ++m)
#pragma unroll
        for (int n = 0; n < 4; ++n)
#pragma unroll
          for (int j = 0; j < 4; ++j) {
            int row = bm + wr * (MR * 16) + m * 16 + kb * 4 + j;
            int col = bn + wc * 64 + n * 16 + fr;
            C[(size_t)row * ldc + col] = acc[m][n][j];
          }
    }
    // rep boundary: next rep first writes sm[0]; last reads here were sm[1] -> disjoint, no barrier
  }
}

// ---------------- local attention (R8 version, unchanged) ----------------
#define HALO 600

__global__ __launch_bounds__(256, 2) void local_attn(const ushort* __restrict__ qkv,
                                                     ushort* __restrict__ aob) {
  __shared__ __align__(16) ushort sh[HALO * 64];   // 76800 B
  const int tile = blockIdx.x;
  const int head = blockIdx.y;
  const int b    = blockIdx.z;
  const int tz = tile >> 4;
  const int ty = (tile >> 2) & 3;
  const int tx = tile & 3;
  const int t0 = tz * 4, h0 = ty * 8, w0 = tx * 8;
  const int tid = threadIdx.x;

  const int tt = tid >> 6;
  const int th = (tid >> 3) & 7;
  const int tw = tid & 7;
  const int n  = (t0 + tt) * 1024 + (h0 + th) * 32 + (w0 + tw);

  for (int rep = 0; rep < REP; ++rep) {
    __syncthreads();   // prior rep's sh reads complete before restage

    for (int idx = tid; idx < HALO; idx += 256) {
      int ht  = idx / 100;
      int rem = idx - ht * 100;
      int hh  = rem / 10;
      int hw  = rem - hh * 10;
      int gt = t0 - 1 + ht, gh = h0 - 1 + hh, gw = w0 - 1 + hw;
      ushort* row = &sh[idx * 64];
      const int sw = idx & 7;
      if (gt >= 0 && gt < TOK_T && gh >= 0 && gh < TOK_H && gw >= 0 && gw < TOK_W) {
        size_t base = ((size_t)b * NTOK + (size_t)gt * 1024 + gh * 32 + gw) * D3;
        const ushort8* ks = (const ushort8*)(qkv + base + DMODEL + head * DHEAD);
        const ushort8* vs = (const ushort8*)(qkv + base + 2 * DMODEL + head * DHEAD);
#pragma unroll
        for (int p = 0; p < 4; ++p) *(ushort8*)&row[(p ^ sw) * 8]       = ks[p];
#pragma unroll
        for (int p = 0; p < 4; ++p) *(ushort8*)&row[((4 + p) ^ sw) * 8] = vs[p];
      } else {
        ushort8 z = (ushort8)0;
#pragma unroll
        for (int s = 0; s < 8; ++s) *(ushort8*)&row[s * 8] = z;
      }
    }

    const ushort* qp = qkv + ((size_t)b * NTOK + n) * D3 + head * DHEAD;
    f32x2 q2[16];
    {
      const ushort8* qs = (const ushort8*)qp;
#pragma unroll
      for (int p = 0; p < 4; ++p) {
        union { ushort8 s; uint4 u; } v; v.s = qs[p];
        q2[p * 4 + 0] = bfpair(v.u.x);
        q2[p * 4 + 1] = bfpair(v.u.y);
        q2[p * 4 + 2] = bfpair(v.u.z);
        q2[p * 4 + 3] = bfpair(v.u.w);
      }
    }
    __syncthreads();

    const float scale = 0.1767766952966369f;  // 1/sqrt(32)
    float s[27];
#pragma unroll
    for (int nb = 0; nb < 27; ++nb) {
      int dt = nb / 9, dh = (nb / 3) % 3, dw = nb % 3;
      int hidx = (tt + dt) * 100 + (th + dh) * 10 + (tw + dw);
      const ushort* row = &sh[hidx * 64];
      const int sw = hidx & 7;
      f32x2 a2 = {0.f, 0.f};
#pragma unroll
      for (int p = 0; p < 4; ++p) {
        union { ushort8 s; uint4 u; } kk; kk.s = *(const ushort8*)&row[(p ^ sw) * 8];
        a2 += q2[p * 4 + 0] * bfpair(kk.u.x);
        a2 += q2[p * 4 + 1] * bfpair(kk.u.y);
        a2 += q2[p * 4 + 2] * bfpair(kk.u.z);
        a2 += q2[p * 4 + 3] * bfpair(kk.u.w);
      }
      s[nb] = (a2[0] + a2[1]) * scale;
    }

    float mx = s[0];
#pragma unroll
    for (int nb = 1; nb < 27; ++nb) mx = fmaxf(mx, s[nb]);

    f32x2 o2[16] = {};
    float sum = 0.f;
#pragma unroll
    for (int nb = 0; nb < 27; ++nb) {
      int dt = nb / 9, dh = (nb / 3) % 3, dw = nb % 3;
      int hidx = (tt + dt) * 100 + (th + dh) * 10 + (tw + dw);
      const ushort* row = &sh[hidx * 64];
      const int sw = hidx & 7;
      float p = __expf(s[nb] - mx);
      sum += p;
      f32x2 p2; p2[0] = p; p2[1] = p;
#pragma unroll
      for (int c = 0; c < 4; ++c) {
        union { ushort8 s; uint4 u; } vv; vv.s = *(const ushort8*)&row[((4 + c) ^ sw) * 8];
        o2[c * 4 + 0] += p2 * bfpair(vv.u.x);
        o2[c * 4 + 1] += p2 * bfpair(vv.u.y);
        o2[c * 4 + 2] += p2 * bfpair(vv.u.z);
        o2[c * 4 + 3] += p2 * bfpair(vv.u.w);
      }
    }

    float inv = 1.f / sum;
    ushort8 os[4];
#pragma unroll
    for (int c = 0; c < 4; ++c)
#pragma unroll
      for (int e = 0; e < 8; ++e)
        os[c][e] = f2bf(o2[c * 4 + (e >> 1)][e & 1] * inv);
    ushort8* op = (ushort8*)(aob + ((size_t)b * NTOK + n) * DMODEL + head * DHEAD);
#pragma unroll
    for (int c = 0; c < 4; ++c) op[c] = os[c];
  }
}

// ---------------- launch ----------------
extern "C" void kernel_launch(void* const* d_in, const int* in_sizes, int n_in,
                              void* d_out, int out_size, void* d_ws, size_t ws_size,
                              hipStream_t stream) {
  const float* x     = (const float*)d_in[0];
  const float* w_qkv = (const float*)d_in[1];
  const float* w_out = (const float*)d_in[2];
  float* out = (float*)d_out;

  char* ws = (char*)d_ws;
  ushort* qkvb = (ushort*)ws;                                   // 24 MB
  ushort* aob  = (ushort*)(ws + (size_t)BATCH * NTOK * D3 * 2); // 8 MB

  // GEMM1: grid (bn=3 fast, bm=128 slow) -> x streamed ~once
  gemm_fused<128, 256, 8, true, true><<<dim3(3, 128), 512, 0, stream>>>(
      (const void*)x, w_qkv, (void*)qkvb, D3);

  // attention: 32 tiles (2x4x4 of 4x8x8) x 8 heads x 2 batch, 2 blocks/CU
  local_attn<<<dim3(32, NHEADS, BATCH), 256, 0, stream>>>(qkvb, aob);

  // GEMM2: grid (bn=2 fast, bm=256 slow) -> aob streamed ~once
  gemm_fused<64, 128, 4, false, false><<<dim3(2, 256), 256, 0, stream>>>(
      (const void*)aob, w_out, (void*)out, DMODEL);
}

// Round 10
// 59.650 us; speedup vs baseline: 9.9631x; 9.9631x over previous
//
#include <hip/hip_runtime.h>
#include <hip/hip_bf16.h>

#define TOK_T 8
#define TOK_H 32
#define TOK_W 32
#define NTOK 8192
#define BATCH 2
#define DMODEL 256
#define D3 768
#define NHEADS 8
#define DHEAD 32

using short8  = __attribute__((ext_vector_type(8))) short;
using ushort8 = __attribute__((ext_vector_type(8))) unsigned short;
using f32x4   = __attribute__((ext_vector_type(4))) float;
using f32x2   = __attribute__((ext_vector_type(2))) float;

__device__ __forceinline__ ushort f2bf(float f) {
  __hip_bfloat16 h = __float2bfloat16(f);
  return *reinterpret_cast<ushort*>(&h);
}
__device__ __forceinline__ float bf2f(ushort u) {
  union { unsigned u; float f; } v; v.u = ((unsigned)u) << 16;
  return v.f;
}
__device__ __forceinline__ f32x2 bfpair(unsigned u) {
  union { unsigned u; float f; } lo, hi;
  lo.u = u << 16;
  hi.u = u & 0xffff0000u;
  f32x2 r; r[0] = lo.f; r[1] = hi.f;
  return r;
}

// ---------------- fused-convert GEMM: C = A[M,256] * B[N,256]^T ----------------
// EPI 0: C = f32 [M][ldc].  EPI 2: qkv-split -> q to qb[tok][256] bf16,
// K/V to kv[b][head][tok][64] bf16 (K at d 0..31, V at 32..63); the q/K/V
// choice is wave-uniform per block (bn panel).
template<int TBM, int TBN, int NW, bool AF32, int EPI>
__global__ __launch_bounds__(NW * 64, 4) void gemm_fused(const void* __restrict__ Av,
                                                         const float* __restrict__ B,
                                                         void* __restrict__ Cv,
                                                         ushort* __restrict__ kv,
                                                         int ldc) {
  constexpr int NCW = TBN / 64;
  constexpr int NWR = NW / NCW;
  constexpr int MR  = TBM / (NWR * 16);
  constexpr int CHA = TBM * 4;
  constexpr int CHB = TBN * 4;
  constexpr int NT  = NW * 64;
  constexpr int CPT = (CHA + CHB) / NT;
  constexpr int SA  = CHA / NT;
  constexpr int ATILE = TBM * 32;
  constexpr int BTILE = TBN * 32;

  __shared__ __align__(16) ushort sm[2][ATILE + BTILE];

  const int tid  = threadIdx.x;
  const int lane = tid & 63;
  const int wid  = tid >> 6;
  const int wr   = wid / NCW;
  const int wc   = wid % NCW;
  const int bm   = blockIdx.y * TBM;   // slow axis
  const int bn   = blockIdx.x * TBN;   // fast axis -> consecutive blocks share A panel
  const int fr   = lane & 15;
  const int kb   = lane >> 4;

  float4  laf[SA > 0 ? SA : 1][2];
  ushort8 lab[SA > 0 ? SA : 1];
  float4  lbf[CPT - SA][2];

  auto load = [&](int kt) {
#pragma unroll
    for (int s = 0; s < SA; ++s) {
      int cc = tid + s * NT;
      int r = cc >> 2, sl = cc & 3;
      if constexpr (AF32) {
        const float* p = (const float*)Av + (size_t)(bm + r) * 256 + kt + sl * 8;
        laf[s][0] = *(const float4*)p;
        laf[s][1] = *(const float4*)(p + 4);
      } else {
        lab[s] = *(const ushort8*)((const ushort*)Av + (size_t)(bm + r) * 256 + kt + sl * 8);
      }
    }
#pragma unroll
    for (int s = 0; s < CPT - SA; ++s) {
      int cc = tid + (s + SA) * NT - CHA;
      int r = cc >> 2, sl = cc & 3;
      const float* p = B + (size_t)(bn + r) * 256 + kt + sl * 8;
      lbf[s][0] = *(const float4*)p;
      lbf[s][1] = *(const float4*)(p + 4);
    }
  };
  auto stow = [&](int buf) {
#pragma unroll
    for (int s = 0; s < SA; ++s) {
      int cc = tid + s * NT;
      int r = cc >> 2, sl = cc & 3;
      int sck = r * 4 + (sl ^ ((r >> 1) & 3));
      ushort8 v;
      if constexpr (AF32) {
        v[0] = f2bf(laf[s][0].x); v[1] = f2bf(laf[s][0].y);
        v[2] = f2bf(laf[s][0].z); v[3] = f2bf(laf[s][0].w);
        v[4] = f2bf(laf[s][1].x); v[5] = f2bf(laf[s][1].y);
        v[6] = f2bf(laf[s][1].z); v[7] = f2bf(laf[s][1].w);
      } else v = lab[s];
      *(ushort8*)&sm[buf][sck * 8] = v;
    }
#pragma unroll
    for (int s = 0; s < CPT - SA; ++s) {
      int cc = tid + (s + SA) * NT - CHA;
      int r = cc >> 2, sl = cc & 3;
      int sck = r * 4 + (sl ^ ((r >> 1) & 3));
      ushort8 v;
      v[0] = f2bf(lbf[s][0].x); v[1] = f2bf(lbf[s][0].y);
      v[2] = f2bf(lbf[s][0].z); v[3] = f2bf(lbf[s][0].w);
      v[4] = f2bf(lbf[s][1].x); v[5] = f2bf(lbf[s][1].y);
      v[6] = f2bf(lbf[s][1].z); v[7] = f2bf(lbf[s][1].w);
      *(ushort8*)&sm[buf][ATILE + sck * 8] = v;
    }
  };

  f32x4 acc[MR][4] = {};

  load(0);
  stow(0);
  __syncthreads();

  for (int it = 0; it < 8; ++it) {
    const int cur = it & 1;
    if (it < 7) load((it + 1) * 32);

    short8 af[MR], bf8[4];
#pragma unroll
    for (int m = 0; m < MR; ++m) {
      int r  = wr * (MR * 16) + m * 16 + fr;
      int ck = r * 4 + (kb ^ ((r >> 1) & 3));
      af[m] = *(const short8*)&sm[cur][ck * 8];
    }
#pragma unroll
    for (int n = 0; n < 4; ++n) {
      int r  = wc * 64 + n * 16 + fr;
      int ck = r * 4 + (kb ^ ((r >> 1) & 3));
      bf8[n] = *(const short8*)&sm[cur][ATILE + ck * 8];
    }
#pragma unroll
    for (int m = 0; m < MR; ++m)
#pragma unroll
      for (int n = 0; n < 4; ++n)
        acc[m][n] = __builtin_amdgcn_mfma_f32_16x16x32_bf16(af[m], bf8[n], acc[m][n], 0, 0, 0);

    if (it < 7) {
      stow(cur ^ 1);
      __syncthreads();
    }
  }

  // epilogue: C/D layout col=lane&15, row=(lane>>4)*4+j
  if constexpr (EPI == 0) {
    float* C = (float*)Cv;
#pragma unroll
    for (int m = 0; m < MR; ++m)
#pragma unroll
      for (int n = 0; n < 4; ++n)
#pragma unroll
        for (int j = 0; j < 4; ++j) {
          int row = bm + wr * (MR * 16) + m * 16 + kb * 4 + j;
          int col = bn + wc * 64 + n * 16 + fr;
          C[(size_t)row * ldc + col] = acc[m][n][j];
        }
  } else {
    ushort* qb = (ushort*)Cv;
    const int typ = bn >> 8;   // 0=q, 1=K, 2=V (wave-uniform; TBN=256)
#pragma unroll
    for (int m = 0; m < MR; ++m)
#pragma unroll
      for (int n = 0; n < 4; ++n)
#pragma unroll
        for (int j = 0; j < 4; ++j) {
          int row = bm + wr * (MR * 16) + m * 16 + kb * 4 + j;
          int col = (bn + wc * 64 + n * 16 + fr) & 255;
          ushort val = f2bf(acc[m][n][j]);
          if (typ == 0) {
            qb[(size_t)row * 256 + col] = val;
          } else {
            int h = col >> 5, d = col & 31;
            int b = row >> 13, tok = row & 8191;
            kv[(((size_t)(b * 8 + h)) * 8192 + tok) * 64 + d + (typ == 2 ? 32 : 0)] = val;
          }
        }
  }
}

// ---------------- local attention, head-major KV + conflict-free LDS ----------------
// One block per (batch, head, 4x8x8 tile); 256 threads = 1 token each.
// kv[b][head][tok][64]: one 128B contiguous row per token (K d0..31, V d32..63).
// Staging: 4864 16B-quads, lane-consecutive = address-consecutive -> coalesced.
// LDS row = 128B, quad s stored at s ^ (row&7) -> conflict-free b128 reads.
#define HALO 600
#define HROWS 608   // padded so 608*8 = 19*256 exactly

__global__ __launch_bounds__(256, 2) void local_attn(const ushort* __restrict__ qb,
                                                     const ushort* __restrict__ kv,
                                                     ushort* __restrict__ aob) {
  __shared__ __align__(16) ushort sh[HROWS * 64];   // 77824 B -> 2 blocks/CU
  const int tile = blockIdx.x;   // 0..31
  const int head = blockIdx.y;
  const int b    = blockIdx.z;
  const int tz = tile >> 4;      // 0..1
  const int ty = (tile >> 2) & 3;
  const int tx = tile & 3;
  const int t0 = tz * 4, h0 = ty * 8, w0 = tx * 8;
  const int tid = threadIdx.x;

  const ushort* kvh = kv + ((size_t)(b * 8 + head)) * 8192 * 64;

  // ---- stage K+V halo: 19 quads per thread, coalesced ----
#pragma unroll
  for (int k = 0; k < 19; ++k) {
    int u   = tid + k * 256;     // 0..4863
    int row = u >> 3;
    int s   = u & 7;
    int ht  = row / 100;
    int rem = row - ht * 100;
    int hh  = rem / 10;
    int hw  = rem - hh * 10;
    int gt = t0 - 1 + ht, gh = h0 - 1 + hh, gw = w0 - 1 + hw;
    uint4 v = {0u, 0u, 0u, 0u};
    if (row < HALO && gt >= 0 && gt < TOK_T && gh >= 0 && gh < TOK_H && gw >= 0 && gw < TOK_W)
      v = *(const uint4*)(kvh + ((size_t)gt * 1024 + gh * 32 + gw) * 64 + s * 8);
    *(uint4*)&sh[row * 64 + ((s ^ (row & 7)) * 8)] = v;
  }

  const int tt = tid >> 6;        // 0..3
  const int th = (tid >> 3) & 7;
  const int tw = tid & 7;
  const int n  = (t0 + tt) * 1024 + (h0 + th) * 32 + (w0 + tw);

  // q in registers as float2 pairs (coalesced 64B per token from qb)
  const ushort* qp = qb + ((size_t)b * NTOK + n) * 256 + head * DHEAD;
  f32x2 q2[16];
  {
    const ushort8* qs = (const ushort8*)qp;
#pragma unroll
    for (int p = 0; p < 4; ++p) {
      union { ushort8 s; uint4 u; } v; v.s = qs[p];
      q2[p * 4 + 0] = bfpair(v.u.x);
      q2[p * 4 + 1] = bfpair(v.u.y);
      q2[p * 4 + 2] = bfpair(v.u.z);
      q2[p * 4 + 3] = bfpair(v.u.w);
    }
  }
  __syncthreads();

  // ---- scores (K quads 0..3, swizzled) ----
  const float scale = 0.1767766952966369f;  // 1/sqrt(32)
  float s[27];
#pragma unroll
  for (int nb = 0; nb < 27; ++nb) {
    int dt = nb / 9, dh = (nb / 3) % 3, dw = nb % 3;
    int hidx = (tt + dt) * 100 + (th + dh) * 10 + (tw + dw);
    const ushort* row = &sh[hidx * 64];
    const int sw = hidx & 7;
    f32x2 a2 = {0.f, 0.f};
#pragma unroll
    for (int p = 0; p < 4; ++p) {
      union { ushort8 s; uint4 u; } kk; kk.s = *(const ushort8*)&row[(p ^ sw) * 8];
      a2 += q2[p * 4 + 0] * bfpair(kk.u.x);
      a2 += q2[p * 4 + 1] * bfpair(kk.u.y);
      a2 += q2[p * 4 + 2] * bfpair(kk.u.z);
      a2 += q2[p * 4 + 3] * bfpair(kk.u.w);
    }
    s[nb] = (a2[0] + a2[1]) * scale;
  }

  float mx = s[0];
#pragma unroll
  for (int nb = 1; nb < 27; ++nb) mx = fmaxf(mx, s[nb]);

  // ---- softmax + PV (V quads 4..7, swizzled) ----
  f32x2 o2[16] = {};
  float sum = 0.f;
#pragma unroll
  for (int nb = 0; nb < 27; ++nb) {
    int dt = nb / 9, dh = (nb / 3) % 3, dw = nb % 3;
    int hidx = (tt + dt) * 100 + (th + dh) * 10 + (tw + dw);
    const ushort* row = &sh[hidx * 64];
    const int sw = hidx & 7;
    float p = __expf(s[nb] - mx);
    sum += p;
    f32x2 p2; p2[0] = p; p2[1] = p;
#pragma unroll
    for (int c = 0; c < 4; ++c) {
      union { ushort8 s; uint4 u; } vv; vv.s = *(const ushort8*)&row[((4 + c) ^ sw) * 8];
      o2[c * 4 + 0] += p2 * bfpair(vv.u.x);
      o2[c * 4 + 1] += p2 * bfpair(vv.u.y);
      o2[c * 4 + 2] += p2 * bfpair(vv.u.z);
      o2[c * 4 + 3] += p2 * bfpair(vv.u.w);
    }
  }

  float inv = 1.f / sum;
  ushort8 os[4];
#pragma unroll
  for (int c = 0; c < 4; ++c)
#pragma unroll
    for (int e = 0; e < 8; ++e)
      os[c][e] = f2bf(o2[c * 4 + (e >> 1)][e & 1] * inv);
  ushort8* op = (ushort8*)(aob + ((size_t)b * NTOK + n) * DMODEL + head * DHEAD);
#pragma unroll
  for (int c = 0; c < 4; ++c) op[c] = os[c];
}

// ---------------- launch ----------------
extern "C" void kernel_launch(void* const* d_in, const int* in_sizes, int n_in,
                              void* d_out, int out_size, void* d_ws, size_t ws_size,
                              hipStream_t stream) {
  const float* x     = (const float*)d_in[0];
  const float* w_qkv = (const float*)d_in[1];
  const float* w_out = (const float*)d_in[2];
  float* out = (float*)d_out;

  char* ws = (char*)d_ws;
  ushort* qb  = (ushort*)ws;                                       // 8 MB  [16384][256]
  ushort* kvb = (ushort*)(ws + (size_t)16384 * 256 * 2);           // 16 MB [2][8][8192][64]
  ushort* aob = (ushort*)(ws + (size_t)16384 * 256 * 2 + (size_t)16 * 8192 * 64 * 2); // 8 MB

  // GEMM1: 64x256 tiles, grid (bn=3 fast, bm=256) = 768 blocks, 4 blocks/CU.
  // Epilogue splits q / K / V into head-major layouts.
  gemm_fused<64, 256, 4, true, 2><<<dim3(3, 256), 256, 0, stream>>>(
      (const void*)x, w_qkv, (void*)qb, kvb, 0);

  // attention: 32 tiles (2x4x4 of 4x8x8) x 8 heads x 2 batch, 2 blocks/CU
  local_attn<<<dim3(32, NHEADS, BATCH), 256, 0, stream>>>(qb, kvb, aob);

  // GEMM2: out = aob(bf16) @ w_out(f32)^T -> f32
  gemm_fused<64, 128, 4, false, 0><<<dim3(2, 256), 256, 0, stream>>>(
      (const void*)aob, w_out, (void*)out, nullptr, DMODEL);
}

// Round 11
// 59.624 us; speedup vs baseline: 9.9674x; 1.0004x over previous
//
#include <hip/hip_runtime.h>
#include <hip/hip_bf16.h>

#define TOK_T 8
#define TOK_H 32
#define TOK_W 32
#define NTOK 8192
#define BATCH 2
#define DMODEL 256
#define D3 768
#define NHEADS 8
#define DHEAD 32

using short8  = __attribute__((ext_vector_type(8))) short;
using ushort8 = __attribute__((ext_vector_type(8))) unsigned short;
using f32x4   = __attribute__((ext_vector_type(4))) float;
using f32x2   = __attribute__((ext_vector_type(2))) float;

__device__ __forceinline__ ushort f2bf(float f) {
  __hip_bfloat16 h = __float2bfloat16(f);
  return *reinterpret_cast<ushort*>(&h);
}
__device__ __forceinline__ float bf2f(ushort u) {
  union { unsigned u; float f; } v; v.u = ((unsigned)u) << 16;
  return v.f;
}
__device__ __forceinline__ f32x2 bfpair(unsigned u) {
  union { unsigned u; float f; } lo, hi;
  lo.u = u << 16;
  hi.u = u & 0xffff0000u;
  f32x2 r; r[0] = lo.f; r[1] = hi.f;
  return r;
}

// ---------------- fused f32 -> bf16 conversion (one launch, 3 arrays) ----------------
#define NX4  (BATCH * NTOK * DMODEL / 4)   // 1048576
#define NW14 (D3 * DMODEL / 4)             // 49152
#define NW24 (DMODEL * DMODEL / 4)         // 16384

__global__ __launch_bounds__(256) void convert_all(const float* __restrict__ x,
                                                   const float* __restrict__ wq,
                                                   const float* __restrict__ wo,
                                                   ushort* __restrict__ xb,
                                                   ushort* __restrict__ wqb,
                                                   ushort* __restrict__ wob) {
  int i = blockIdx.x * 256 + threadIdx.x;
  const float* src; ushort* dst; int j;
  if (i < NX4)              { src = x;  dst = xb;  j = i; }
  else if (i < NX4 + NW14)  { src = wq; dst = wqb; j = i - NX4; }
  else if (i < NX4 + NW14 + NW24) { src = wo; dst = wob; j = i - NX4 - NW14; }
  else return;
  float4 v = ((const float4*)src)[j];
  ushort4 o;
  o.x = f2bf(v.x); o.y = f2bf(v.y); o.z = f2bf(v.z); o.w = f2bf(v.w);
  ((ushort4*)dst)[j] = o;
}

// ---------------- bf16 GEMM, C = A[M,K] * B[N,K]^T (R2-proven kernel) ----------------
// TBM x TBN tile, BK=32, NW waves, each wave a 64x64 sub-tile (wr=wid/NCW, wc=wid%NCW).
// global_load_lds staging (linear LDS dest + inverse-swizzled global source),
// double-buffered; ds_read slot swizzle ck = r*4 + (kb ^ ((r>>1)&3)).
// bn = blockIdx.x (fast) -> consecutive blocks share the A panel.
#define BKK 32

template<int TBM, int TBN, int NW, bool OUT_BF16>
__global__ __launch_bounds__(NW * 64) void gemm_bt(const ushort* __restrict__ A,
                                                   const ushort* __restrict__ B,
                                                   void* __restrict__ Cv,
                                                   int N, int K) {
  __shared__ __align__(16) ushort sA[2][TBM * BKK];
  __shared__ __align__(16) ushort sB[2][TBN * BKK];
  constexpr int NCW = TBN / 64;
  constexpr int CHA = TBM * 4;
  constexpr int CHB = TBN * 4;
  constexpr int CH  = CHA + CHB;
  constexpr int NT  = NW * 64;

  const int tid  = threadIdx.x;
  const int lane = tid & 63;
  const int wid  = tid >> 6;
  const int wr   = wid / NCW;
  const int wc   = wid % NCW;
  const int bm   = blockIdx.y * TBM;   // slow
  const int bn   = blockIdx.x * TBN;   // fast
  const int fr   = lane & 15;
  const int kb   = lane >> 4;

  f32x4 acc[4][4] = {};

  auto stage = [&](int buf, int kt) {
#pragma unroll
    for (int c0 = 0; c0 < CH; c0 += NT) {
      int c  = c0 + tid;
      int cb = c - lane;               // wave-uniform chunk base
      bool isA = (c < CHA);            // wave-uniform (CHA multiple of 64)
      int cc  = isA ? c  : c - CHA;
      int cbb = isA ? cb : cb - CHA;
      int r  = cc >> 2;
      int sl = cc & 3;
      int ss = sl ^ ((r >> 1) & 3);    // inverse-swizzled source slot
      const ushort* src = (isA ? A + (size_t)(bm + r) * K
                               : B + (size_t)(bn + r) * K) + kt + ss * 8;
      ushort* dst = isA ? &sA[buf][cbb * 8] : &sB[buf][cbb * 8];
      __builtin_amdgcn_global_load_lds((const __attribute__((address_space(1))) void*)src,
                                       (__attribute__((address_space(3))) void*)dst, 16, 0, 0);
    }
  };

  const int nit = K >> 5;
  stage(0, 0);
  __syncthreads();

  for (int it = 0; it < nit; ++it) {
    const int cur = it & 1;
    if (it + 1 < nit) stage(cur ^ 1, (it + 1) << 5);   // prefetch next tile

    short8 af[4], bfr[4];
#pragma unroll
    for (int m = 0; m < 4; ++m) {
      int r  = wr * 64 + m * 16 + fr;
      int ck = r * 4 + (kb ^ ((r >> 1) & 3));
      af[m] = *(const short8*)&sA[cur][ck * 8];
    }
#pragma unroll
    for (int n = 0; n < 4; ++n) {
      int r  = wc * 64 + n * 16 + fr;
      int ck = r * 4 + (kb ^ ((r >> 1) & 3));
      bfr[n] = *(const short8*)&sB[cur][ck * 8];
    }
#pragma unroll
    for (int m = 0; m < 4; ++m)
#pragma unroll
      for (int n = 0; n < 4; ++n)
        acc[m][n] = __builtin_amdgcn_mfma_f32_16x16x32_bf16(af[m], bfr[n], acc[m][n], 0, 0, 0);
    __syncthreads();
  }

  // epilogue: C/D layout col=lane&15, row=(lane>>4)*4+j
  if constexpr (OUT_BF16) {
    ushort* C = (ushort*)Cv;
#pragma unroll
    for (int m = 0; m < 4; ++m)
#pragma unroll
      for (int n = 0; n < 4; ++n)
#pragma unroll
        for (int j = 0; j < 4; ++j) {
          int row = bm + wr * 64 + m * 16 + kb * 4 + j;
          int col = bn + wc * 64 + n * 16 + fr;
          C[(size_t)row * N + col] = f2bf(acc[m][n][j]);
        }
  } else {
    float* C = (float*)Cv;
#pragma unroll
    for (int m = 0; m < 4; ++m)
#pragma unroll
      for (int n = 0; n < 4; ++n)
#pragma unroll
        for (int j = 0; j < 4; ++j) {
          int row = bm + wr * 64 + m * 16 + kb * 4 + j;
          int col = bn + wc * 64 + n * 16 + fr;
          C[(size_t)row * N + col] = acc[m][n][j];
        }
  }
}

// ---------------- local attention (R8 kernel + XCD-aware block mapping) ----------------
// 512 blocks 1D. grp = bid&7 = tz*4+ty: each XCD owns one contiguous 4x8x32
// spatial slab (+halo ~3.1MB < 4MB L2) for ALL heads/batches -> token-major
// qkv rows (1536B, shared by all 8 heads) stay resident in the owning XCD's L2.
// LDS: one 128B row per halo token, quad s at slot s^(row&7). 76.8KB, 2 blocks/CU.
#define HALO 600

__global__ __launch_bounds__(256, 2) void local_attn(const ushort* __restrict__ qkv,
                                                     ushort* __restrict__ aob) {
  __shared__ __align__(16) ushort sh[HALO * 64];
  const int bid  = blockIdx.x;
  const int grp  = bid & 7;        // XCD id = tz*4 + ty
  const int slot = bid >> 3;       // 0..63
  const int tz = grp >> 2, ty = grp & 3;
  const int tx   = slot & 3;
  const int head = (slot >> 2) & 7;
  const int b    = slot >> 5;
  const int t0 = tz * 4, h0 = ty * 8, w0 = tx * 8;
  const int tid = threadIdx.x;

  // ---- stage K+V halo: 4800 16B-quad tasks; 8 consecutive lanes = one row's
  // 8 quads (two contiguous 64B segments) -> full-line L2 reads ----
#pragma unroll
  for (int k = 0; k < 19; ++k) {
    int u = tid + k * 256;
    if (u < HALO * 8) {
      int row = u >> 3;
      int q   = u & 7;
      int ht  = row / 100;
      int rem = row - ht * 100;
      int hh  = rem / 10;
      int hw  = rem - hh * 10;
      int gt = t0 - 1 + ht, gh = h0 - 1 + hh, gw = w0 - 1 + hw;
      uint4 v = {0u, 0u, 0u, 0u};
      if (gt >= 0 && gt < TOK_T && gh >= 0 && gh < TOK_H && gw >= 0 && gw < TOK_W) {
        size_t base = ((size_t)b * NTOK + (size_t)gt * 1024 + gh * 32 + gw) * D3
                      + head * DHEAD + (q < 4 ? DMODEL + q * 8 : 2 * DMODEL + (q - 4) * 8);
        v = *(const uint4*)(qkv + base);
      }
      *(uint4*)&sh[row * 64 + ((q ^ (row & 7)) * 8)] = v;
    }
  }

  const int tt = tid >> 6;        // 0..3
  const int th = (tid >> 3) & 7;
  const int tw = tid & 7;
  const int n  = (t0 + tt) * 1024 + (h0 + th) * 32 + (w0 + tw);

  // q in registers as float2 pairs
  const ushort* qp = qkv + ((size_t)b * NTOK + n) * D3 + head * DHEAD;
  f32x2 q2[16];
  {
    const ushort8* qs = (const ushort8*)qp;
#pragma unroll
    for (int p = 0; p < 4; ++p) {
      union { ushort8 s; uint4 u; } v; v.s = qs[p];
      q2[p * 4 + 0] = bfpair(v.u.x);
      q2[p * 4 + 1] = bfpair(v.u.y);
      q2[p * 4 + 2] = bfpair(v.u.z);
      q2[p * 4 + 3] = bfpair(v.u.w);
    }
  }
  __syncthreads();

  // ---- scores (K quads 0..3, swizzled) ----
  const float scale = 0.1767766952966369f;  // 1/sqrt(32)
  float s[27];
#pragma unroll
  for (int nb = 0; nb < 27; ++nb) {
    int dt = nb / 9, dh = (nb / 3) % 3, dw = nb % 3;
    int hidx = (tt + dt) * 100 + (th + dh) * 10 + (tw + dw);
    const ushort* row = &sh[hidx * 64];
    const int sw = hidx & 7;
    f32x2 a2 = {0.f, 0.f};
#pragma unroll
    for (int p = 0; p < 4; ++p) {
      union { ushort8 s; uint4 u; } kk; kk.s = *(const ushort8*)&row[(p ^ sw) * 8];
      a2 += q2[p * 4 + 0] * bfpair(kk.u.x);
      a2 += q2[p * 4 + 1] * bfpair(kk.u.y);
      a2 += q2[p * 4 + 2] * bfpair(kk.u.z);
      a2 += q2[p * 4 + 3] * bfpair(kk.u.w);
    }
    s[nb] = (a2[0] + a2[1]) * scale;
  }

  float mx = s[0];
#pragma unroll
  for (int nb = 1; nb < 27; ++nb) mx = fmaxf(mx, s[nb]);

  // ---- softmax + PV (V quads 4..7, swizzled) ----
  f32x2 o2[16] = {};
  float sum = 0.f;
#pragma unroll
  for (int nb = 0; nb < 27; ++nb) {
    int dt = nb / 9, dh = (nb / 3) % 3, dw = nb % 3;
    int hidx = (tt + dt) * 100 + (th + dh) * 10 + (tw + dw);
    const ushort* row = &sh[hidx * 64];
    const int sw = hidx & 7;
    float p = __expf(s[nb] - mx);
    sum += p;
    f32x2 p2; p2[0] = p; p2[1] = p;
#pragma unroll
    for (int c = 0; c < 4; ++c) {
      union { ushort8 s; uint4 u; } vv; vv.s = *(const ushort8*)&row[((4 + c) ^ sw) * 8];
      o2[c * 4 + 0] += p2 * bfpair(vv.u.x);
      o2[c * 4 + 1] += p2 * bfpair(vv.u.y);
      o2[c * 4 + 2] += p2 * bfpair(vv.u.z);
      o2[c * 4 + 3] += p2 * bfpair(vv.u.w);
    }
  }

  float inv = 1.f / sum;
  ushort8 os[4];
#pragma unroll
  for (int c = 0; c < 4; ++c)
#pragma unroll
    for (int e = 0; e < 8; ++e)
      os[c][e] = f2bf(o2[c * 4 + (e >> 1)][e & 1] * inv);
  ushort8* op = (ushort8*)(aob + ((size_t)b * NTOK + n) * DMODEL + head * DHEAD);
#pragma unroll
  for (int c = 0; c < 4; ++c) op[c] = os[c];
}

// ---------------- launch ----------------
extern "C" void kernel_launch(void* const* d_in, const int* in_sizes, int n_in,
                              void* d_out, int out_size, void* d_ws, size_t ws_size,
                              hipStream_t stream) {
  const float* x     = (const float*)d_in[0];
  const float* w_qkv = (const float*)d_in[1];
  const float* w_out = (const float*)d_in[2];
  float* out = (float*)d_out;

  char* ws = (char*)d_ws;
  size_t off = 0;
  ushort* xb    = (ushort*)(ws + off); off += (size_t)BATCH * NTOK * DMODEL * 2;  // 8 MB
  ushort* wqkvb = (ushort*)(ws + off); off += (size_t)D3 * DMODEL * 2;
  ushort* woutb = (ushort*)(ws + off); off += (size_t)DMODEL * DMODEL * 2;
  ushort* qkvb  = (ushort*)(ws + off); off += (size_t)BATCH * NTOK * D3 * 2;      // 24 MB
  ushort* aob   = (ushort*)(ws + off); off += (size_t)BATCH * NTOK * DMODEL * 2;  // 8 MB

  int ntot = NX4 + NW14 + NW24;
  convert_all<<<(ntot + 255) / 256, 256, 0, stream>>>(x, w_qkv, w_out, xb, wqkvb, woutb);

  // GEMM1: 128x256 tiles, grid (bn=3 fast, bm=128) -> x panel shared by consecutive blocks
  gemm_bt<128, 256, 8, true><<<dim3(3, 128), 512, 0, stream>>>(xb, wqkvb, (void*)qkvb,
                                                               D3, DMODEL);

  // attention: 512 blocks, XCD-grouped spatial slabs
  local_attn<<<512, 256, 0, stream>>>(qkvb, aob);

  // GEMM2: 64x256 tile covers all of N=256 -> w_out staged once per block
  gemm_bt<64, 256, 4, false><<<dim3(1, 256), 256, 0, stream>>>(aob, woutb, (void*)out,
                                                               DMODEL, DMODEL);
}

// Round 12
// 55.702 us; speedup vs baseline: 10.6693x; 1.0704x over previous
//
#include <hip/hip_runtime.h>
#include <hip/hip_bf16.h>

#define TOK_T 8
#define TOK_H 32
#define TOK_W 32
#define NTOK 8192
#define BATCH 2
#define DMODEL 256
#define D3 768
#define NHEADS 8
#define DHEAD 32

using short8  = __attribute__((ext_vector_type(8))) short;
using ushort8 = __attribute__((ext_vector_type(8))) unsigned short;
using f32x4   = __attribute__((ext_vector_type(4))) float;
using f32x2   = __attribute__((ext_vector_type(2))) float;

__device__ __forceinline__ ushort f2bf(float f) {
  __hip_bfloat16 h = __float2bfloat16(f);
  return *reinterpret_cast<ushort*>(&h);
}
__device__ __forceinline__ float bf2f(ushort u) {
  union { unsigned u; float f; } v; v.u = ((unsigned)u) << 16;
  return v.f;
}
__device__ __forceinline__ f32x2 bfpair(unsigned u) {
  union { unsigned u; float f; } lo, hi;
  lo.u = u << 16;
  hi.u = u & 0xffff0000u;
  f32x2 r; r[0] = lo.f; r[1] = hi.f;
  return r;
}

// ---------------- fused-convert GEMM: C = A[M,256] * B[N,256]^T ----------------
// 1D grid with XCD-colocating remap: xcd = bm&7, id = xcd + 8*((bm>>3)*NBN + bn).
// All NBN blocks sharing an A panel land on ONE XCD -> panel fetched from HBM
// once (per-XCD L2 keeps it). NBM must be a multiple of 8.
template<int TBM, int TBN, int NW, int NBN, bool AF32, bool OUTBF16>
__global__ __launch_bounds__(NW * 64, 4) void gemm_fused(const void* __restrict__ Av,
                                                         const float* __restrict__ B,
                                                         void* __restrict__ Cv,
                                                         int ldc) {
  constexpr int NCW = TBN / 64;
  constexpr int NWR = NW / NCW;
  constexpr int MR  = TBM / (NWR * 16);
  constexpr int CHA = TBM * 4;
  constexpr int CHB = TBN * 4;
  constexpr int NT  = NW * 64;
  constexpr int CPT = (CHA + CHB) / NT;
  constexpr int SA  = CHA / NT;
  constexpr int ATILE = TBM * 32;
  constexpr int BTILE = TBN * 32;

  __shared__ __align__(16) ushort sm[2][ATILE + BTILE];

  const int tid  = threadIdx.x;
  const int lane = tid & 63;
  const int wid  = tid >> 6;
  const int wr   = wid / NCW;
  const int wc   = wid % NCW;
  // XCD-colocating decode
  const int bid  = blockIdx.x;
  const int xcd  = bid & 7;
  const int kk2  = bid >> 3;
  const int bm   = ((kk2 / NBN) * 8 + xcd) * TBM;
  const int bn   = (kk2 % NBN) * TBN;
  const int fr   = lane & 15;
  const int kb   = lane >> 4;

  float4  laf[SA > 0 ? SA : 1][2];
  ushort8 lab[SA > 0 ? SA : 1];
  float4  lbf[CPT - SA][2];

  auto load = [&](int kt) {
#pragma unroll
    for (int s = 0; s < SA; ++s) {
      int cc = tid + s * NT;
      int r = cc >> 2, sl = cc & 3;
      if constexpr (AF32) {
        const float* p = (const float*)Av + (size_t)(bm + r) * 256 + kt + sl * 8;
        laf[s][0] = *(const float4*)p;
        laf[s][1] = *(const float4*)(p + 4);
      } else {
        lab[s] = *(const ushort8*)((const ushort*)Av + (size_t)(bm + r) * 256 + kt + sl * 8);
      }
    }
#pragma unroll
    for (int s = 0; s < CPT - SA; ++s) {
      int cc = tid + (s + SA) * NT - CHA;
      int r = cc >> 2, sl = cc & 3;
      const float* p = B + (size_t)(bn + r) * 256 + kt + sl * 8;
      lbf[s][0] = *(const float4*)p;
      lbf[s][1] = *(const float4*)(p + 4);
    }
  };
  auto stow = [&](int buf) {
#pragma unroll
    for (int s = 0; s < SA; ++s) {
      int cc = tid + s * NT;
      int r = cc >> 2, sl = cc & 3;
      int sck = r * 4 + (sl ^ ((r >> 1) & 3));
      ushort8 v;
      if constexpr (AF32) {
        v[0] = f2bf(laf[s][0].x); v[1] = f2bf(laf[s][0].y);
        v[2] = f2bf(laf[s][0].z); v[3] = f2bf(laf[s][0].w);
        v[4] = f2bf(laf[s][1].x); v[5] = f2bf(laf[s][1].y);
        v[6] = f2bf(laf[s][1].z); v[7] = f2bf(laf[s][1].w);
      } else v = lab[s];
      *(ushort8*)&sm[buf][sck * 8] = v;
    }
#pragma unroll
    for (int s = 0; s < CPT - SA; ++s) {
      int cc = tid + (s + SA) * NT - CHA;
      int r = cc >> 2, sl = cc & 3;
      int sck = r * 4 + (sl ^ ((r >> 1) & 3));
      ushort8 v;
      v[0] = f2bf(lbf[s][0].x); v[1] = f2bf(lbf[s][0].y);
      v[2] = f2bf(lbf[s][0].z); v[3] = f2bf(lbf[s][0].w);
      v[4] = f2bf(lbf[s][1].x); v[5] = f2bf(lbf[s][1].y);
      v[6] = f2bf(lbf[s][1].z); v[7] = f2bf(lbf[s][1].w);
      *(ushort8*)&sm[buf][ATILE + sck * 8] = v;
    }
  };

  f32x4 acc[MR][4] = {};

  load(0);
  stow(0);
  __syncthreads();

  for (int it = 0; it < 8; ++it) {
    const int cur = it & 1;
    if (it < 7) load((it + 1) * 32);   // issue next-tile global loads early

    short8 af[MR], bf8[4];
#pragma unroll
    for (int m = 0; m < MR; ++m) {
      int r  = wr * (MR * 16) + m * 16 + fr;
      int ck = r * 4 + (kb ^ ((r >> 1) & 3));
      af[m] = *(const short8*)&sm[cur][ck * 8];
    }
#pragma unroll
    for (int n = 0; n < 4; ++n) {
      int r  = wc * 64 + n * 16 + fr;
      int ck = r * 4 + (kb ^ ((r >> 1) & 3));
      bf8[n] = *(const short8*)&sm[cur][ATILE + ck * 8];
    }
#pragma unroll
    for (int m = 0; m < MR; ++m)
#pragma unroll
      for (int n = 0; n < 4; ++n)
        acc[m][n] = __builtin_amdgcn_mfma_f32_16x16x32_bf16(af[m], bf8[n], acc[m][n], 0, 0, 0);

    if (it < 7) {
      stow(cur ^ 1);
      __syncthreads();
    }
  }

  if constexpr (OUTBF16) {
    ushort* C = (ushort*)Cv;
#pragma unroll
    for (int m = 0; m < MR; ++m)
#pragma unroll
      for (int n = 0; n < 4; ++n)
#pragma unroll
        for (int j = 0; j < 4; ++j) {
          int row = bm + wr * (MR * 16) + m * 16 + kb * 4 + j;
          int col = bn + wc * 64 + n * 16 + fr;
          C[(size_t)row * ldc + col] = f2bf(acc[m][n][j]);
        }
  } else {
    float* C = (float*)Cv;
#pragma unroll
    for (int m = 0; m < MR; ++m)
#pragma unroll
      for (int n = 0; n < 4; ++n)
#pragma unroll
        for (int j = 0; j < 4; ++j) {
          int row = bm + wr * (MR * 16) + m * 16 + kb * 4 + j;
          int col = bn + wc * 64 + n * 16 + fr;
          C[(size_t)row * ldc + col] = acc[m][n][j];
        }
  }
}

// ---------------- local attention (exact R8 kernel) ----------------
#define HALO 600

__global__ __launch_bounds__(256, 2) void local_attn(const ushort* __restrict__ qkv,
                                                     ushort* __restrict__ aob) {
  __shared__ __align__(16) ushort sh[HALO * 64];   // 76800 B, 2 blocks/CU
  const int tile = blockIdx.x;
  const int head = blockIdx.y;
  const int b    = blockIdx.z;
  const int tz = tile >> 4;
  const int ty = (tile >> 2) & 3;
  const int tx = tile & 3;
  const int t0 = tz * 4, h0 = ty * 8, w0 = tx * 8;
  const int tid = threadIdx.x;

  for (int idx = tid; idx < HALO; idx += 256) {
    int ht  = idx / 100;
    int rem = idx - ht * 100;
    int hh  = rem / 10;
    int hw  = rem - hh * 10;
    int gt = t0 - 1 + ht, gh = h0 - 1 + hh, gw = w0 - 1 + hw;
    ushort* row = &sh[idx * 64];
    const int sw = idx & 7;
    if (gt >= 0 && gt < TOK_T && gh >= 0 && gh < TOK_H && gw >= 0 && gw < TOK_W) {
      size_t base = ((size_t)b * NTOK + (size_t)gt * 1024 + gh * 32 + gw) * D3;
      const ushort8* ks = (const ushort8*)(qkv + base + DMODEL + head * DHEAD);
      const ushort8* vs = (const ushort8*)(qkv + base + 2 * DMODEL + head * DHEAD);
#pragma unroll
      for (int p = 0; p < 4; ++p) *(ushort8*)&row[(p ^ sw) * 8]       = ks[p];
#pragma unroll
      for (int p = 0; p < 4; ++p) *(ushort8*)&row[((4 + p) ^ sw) * 8] = vs[p];
    } else {
      ushort8 z = (ushort8)0;
#pragma unroll
      for (int s = 0; s < 8; ++s) *(ushort8*)&row[s * 8] = z;
    }
  }

  const int tt = tid >> 6;
  const int th = (tid >> 3) & 7;
  const int tw = tid & 7;
  const int n  = (t0 + tt) * 1024 + (h0 + th) * 32 + (w0 + tw);

  const ushort* qp = qkv + ((size_t)b * NTOK + n) * D3 + head * DHEAD;
  f32x2 q2[16];
  {
    const ushort8* qs = (const ushort8*)qp;
#pragma unroll
    for (int p = 0; p < 4; ++p) {
      union { ushort8 s; uint4 u; } v; v.s = qs[p];
      q2[p * 4 + 0] = bfpair(v.u.x);
      q2[p * 4 + 1] = bfpair(v.u.y);
      q2[p * 4 + 2] = bfpair(v.u.z);
      q2[p * 4 + 3] = bfpair(v.u.w);
    }
  }
  __syncthreads();

  const float scale = 0.1767766952966369f;  // 1/sqrt(32)
  float s[27];
#pragma unroll
  for (int nb = 0; nb < 27; ++nb) {
    int dt = nb / 9, dh = (nb / 3) % 3, dw = nb % 3;
    int hidx = (tt + dt) * 100 + (th + dh) * 10 + (tw + dw);
    const ushort* row = &sh[hidx * 64];
    const int sw = hidx & 7;
    f32x2 a2 = {0.f, 0.f};
#pragma unroll
    for (int p = 0; p < 4; ++p) {
      union { ushort8 s; uint4 u; } kk; kk.s = *(const ushort8*)&row[(p ^ sw) * 8];
      a2 += q2[p * 4 + 0] * bfpair(kk.u.x);
      a2 += q2[p * 4 + 1] * bfpair(kk.u.y);
      a2 += q2[p * 4 + 2] * bfpair(kk.u.z);
      a2 += q2[p * 4 + 3] * bfpair(kk.u.w);
    }
    s[nb] = (a2[0] + a2[1]) * scale;
  }

  float mx = s[0];
#pragma unroll
  for (int nb = 1; nb < 27; ++nb) mx = fmaxf(mx, s[nb]);

  f32x2 o2[16] = {};
  float sum = 0.f;
#pragma unroll
  for (int nb = 0; nb < 27; ++nb) {
    int dt = nb / 9, dh = (nb / 3) % 3, dw = nb % 3;
    int hidx = (tt + dt) * 100 + (th + dh) * 10 + (tw + dw);
    const ushort* row = &sh[hidx * 64];
    const int sw = hidx & 7;
    float p = __expf(s[nb] - mx);
    sum += p;
    f32x2 p2; p2[0] = p; p2[1] = p;
#pragma unroll
    for (int c = 0; c < 4; ++c) {
      union { ushort8 s; uint4 u; } vv; vv.s = *(const ushort8*)&row[((4 + c) ^ sw) * 8];
      o2[c * 4 + 0] += p2 * bfpair(vv.u.x);
      o2[c * 4 + 1] += p2 * bfpair(vv.u.y);
      o2[c * 4 + 2] += p2 * bfpair(vv.u.z);
      o2[c * 4 + 3] += p2 * bfpair(vv.u.w);
    }
  }

  float inv = 1.f / sum;
  ushort8 os[4];
#pragma unroll
  for (int c = 0; c < 4; ++c)
#pragma unroll
    for (int e = 0; e < 8; ++e)
      os[c][e] = f2bf(o2[c * 4 + (e >> 1)][e & 1] * inv);
  ushort8* op = (ushort8*)(aob + ((size_t)b * NTOK + n) * DMODEL + head * DHEAD);
#pragma unroll
  for (int c = 0; c < 4; ++c) op[c] = os[c];
}

// ---------------- launch ----------------
extern "C" void kernel_launch(void* const* d_in, const int* in_sizes, int n_in,
                              void* d_out, int out_size, void* d_ws, size_t ws_size,
                              hipStream_t stream) {
  const float* x     = (const float*)d_in[0];
  const float* w_qkv = (const float*)d_in[1];
  const float* w_out = (const float*)d_in[2];
  float* out = (float*)d_out;

  char* ws = (char*)d_ws;
  ushort* qkvb = (ushort*)ws;                                   // 24 MB
  ushort* aob  = (ushort*)(ws + (size_t)BATCH * NTOK * D3 * 2); // 8 MB

  // GEMM1: 128x256 tiles, 1D grid 384, XCD-colocated (NBM=128 mult of 8, NBN=3)
  gemm_fused<128, 256, 8, 3, true, true><<<384, 512, 0, stream>>>(
      (const void*)x, w_qkv, (void*)qkvb, D3);

  // attention: exact R8 config
  local_attn<<<dim3(32, NHEADS, BATCH), 256, 0, stream>>>(qkvb, aob);

  // GEMM2: 64x128 tiles, 1D grid 512, XCD-colocated (NBM=256 mult of 8, NBN=2)
  gemm_fused<64, 128, 4, 2, false, false><<<512, 256, 0, stream>>>(
      (const void*)aob, w_out, (void*)out, DMODEL);
}